// Round 1
// baseline (2183.338 us; speedup 1.0000x reference)
//
#include <hip/hip_runtime.h>
#include <cstdint>
#include <cstddef>

#define F_IN  512
#define F_HID 256
#define F_OUT 40

// ---------------------------------------------------------------------------
// Graph preprocessing: degree count, dinv, CSR build (re-done every call; the
// harness re-poisons d_ws, so nothing survives between launches).
// ---------------------------------------------------------------------------

__global__ void count_kernel(const int* __restrict__ row, const int* __restrict__ col,
                             int* __restrict__ cnt_row, int* __restrict__ cnt_col, int E) {
    int e = blockIdx.x * blockDim.x + threadIdx.x;
    if (e < E) {
        atomicAdd(&cnt_row[row[e]], 1);
        atomicAdd(&cnt_col[col[e]], 1);
    }
}

// deg = (#edges with col==i) + 1 self-loop; deg >= 1 always so no zero guard.
__global__ void dinv_kernel(const int* __restrict__ cnt_col, float* __restrict__ dinv, int N) {
    int i = blockIdx.x * blockDim.x + threadIdx.x;
    if (i < N) dinv[i] = rsqrtf((float)(cnt_col[i] + 1));
}

// Single-block exclusive scan of cnt_row -> rowptr[N+1]; cursor = copy for scatter.
__global__ __launch_bounds__(1024) void scan_kernel(const int* __restrict__ cnt,
                                                    int* __restrict__ rowptr,
                                                    int* __restrict__ cursor, int N) {
    __shared__ int sums[1024];
    int tid = threadIdx.x;
    int chunk = (N + 1023) >> 10;
    int s0 = tid * chunk;
    int s1 = s0 + chunk;
    if (s0 > N) s0 = N;
    if (s1 > N) s1 = N;
    int sum = 0;
    for (int i = s0; i < s1; ++i) sum += cnt[i];
    sums[tid] = sum;
    __syncthreads();
    // Hillis-Steele inclusive scan over the 1024 partial sums
    for (int off = 1; off < 1024; off <<= 1) {
        int v = (tid >= off) ? sums[tid - off] : 0;
        __syncthreads();
        sums[tid] += v;
        __syncthreads();
    }
    int base = (tid > 0) ? sums[tid - 1] : 0;
    for (int i = s0; i < s1; ++i) {
        rowptr[i] = base;
        cursor[i] = base;
        base += cnt[i];
    }
    if (tid == 0) rowptr[N] = sums[1023];
}

__global__ void scatter_kernel(const int* __restrict__ row, const int* __restrict__ col,
                               const float* __restrict__ dinv, int* __restrict__ cursor,
                               int* __restrict__ col_s, float* __restrict__ norm_s, int E) {
    int e = blockIdx.x * blockDim.x + threadIdx.x;
    if (e < E) {
        int r = row[e];
        int c = col[e];
        int pos = atomicAdd(&cursor[r], 1);
        col_s[pos]  = c;
        norm_s[pos] = dinv[r] * dinv[c];
    }
}

// ---------------------------------------------------------------------------
// GEMM1: h = x @ W1   (M x 512) @ (512 x 256), fp32, tiled 64x64, BK=16.
// 256 threads, each computes a 4x4 register tile. LDS rows padded to 68 floats
// so float4 LDS reads are 16B-aligned and conflict-light.
// ---------------------------------------------------------------------------

__global__ __launch_bounds__(256) void gemm1_kernel(const float* __restrict__ A,
                                                    const float* __restrict__ B,
                                                    float* __restrict__ C, int M) {
    __shared__ float As[16][68];  // transposed: As[k][m]
    __shared__ float Bs[16][68];  // Bs[k][n]
    const int tid = threadIdx.x;
    const int bm = blockIdx.y * 64;
    const int bn = blockIdx.x * 64;
    const int tx = tid & 15;      // 16 col groups
    const int ty = tid >> 4;      // 16 row groups
    float acc[4][4] = {};

    const int ar = tid >> 2;          // 0..63 : tile row this thread stages
    const int ak = (tid & 3) * 4;     // 0,4,8,12 : k offset staged
    const int bk = tid >> 4;          // 0..15 : k row of B staged
    const int bn2 = (tid & 15) * 4;   // col offset staged

    for (int k0 = 0; k0 < F_IN; k0 += 16) {
        float4 av = make_float4(0.f, 0.f, 0.f, 0.f);
        int gr = bm + ar;
        if (gr < M) av = *(const float4*)(A + (size_t)gr * F_IN + k0 + ak);
        As[ak + 0][ar] = av.x;
        As[ak + 1][ar] = av.y;
        As[ak + 2][ar] = av.z;
        As[ak + 3][ar] = av.w;
        float4 bv = *(const float4*)(B + (size_t)(k0 + bk) * F_HID + bn + bn2);
        *(float4*)&Bs[bk][bn2] = bv;
        __syncthreads();
#pragma unroll
        for (int kk = 0; kk < 16; ++kk) {
            float4 a4 = *(const float4*)&As[kk][ty * 4];
            float4 b4 = *(const float4*)&Bs[kk][tx * 4];
            float ar_[4] = {a4.x, a4.y, a4.z, a4.w};
            float br_[4] = {b4.x, b4.y, b4.z, b4.w};
#pragma unroll
            for (int i = 0; i < 4; ++i)
#pragma unroll
                for (int j = 0; j < 4; ++j) acc[i][j] = fmaf(ar_[i], br_[j], acc[i][j]);
        }
        __syncthreads();
    }
#pragma unroll
    for (int i = 0; i < 4; ++i) {
        int gr = bm + ty * 4 + i;
        if (gr < M) {
            *(float4*)(C + (size_t)gr * F_HID + bn + tx * 4) =
                make_float4(acc[i][0], acc[i][1], acc[i][2], acc[i][3]);
        }
    }
}

// ---------------------------------------------------------------------------
// Propagate layer 1 (F=256) + bias + ReLU. One wave per row; lane holds 4
// consecutive features (float4) -> each neighbor gather is a fully coalesced
// 1 KB row read.
// ---------------------------------------------------------------------------

__global__ __launch_bounds__(256) void prop1_kernel(const float* __restrict__ h,
                                                    const float* __restrict__ b1,
                                                    const float* __restrict__ dinv,
                                                    const int* __restrict__ rowptr,
                                                    const int* __restrict__ col_s,
                                                    const float* __restrict__ norm_s,
                                                    float* __restrict__ g, int N) {
    int wid  = (blockIdx.x * blockDim.x + threadIdx.x) >> 6;
    int lane = threadIdx.x & 63;
    if (wid >= N) return;
    float di = dinv[wid];
    float sn = di * di;  // self-loop norm
    float4 acc = ((const float4*)(h + (size_t)wid * F_HID))[lane];
    acc.x *= sn; acc.y *= sn; acc.z *= sn; acc.w *= sn;
    int e0 = rowptr[wid], e1 = rowptr[wid + 1];
    for (int e = e0; e < e1; ++e) {
        int   c = col_s[e];    // uniform across wave -> HW broadcast
        float w = norm_s[e];
        float4 v = ((const float4*)(h + (size_t)c * F_HID))[lane];
        acc.x = fmaf(w, v.x, acc.x);
        acc.y = fmaf(w, v.y, acc.y);
        acc.z = fmaf(w, v.z, acc.z);
        acc.w = fmaf(w, v.w, acc.w);
    }
    float4 bv = ((const float4*)b1)[lane];
    acc.x = fmaxf(acc.x + bv.x, 0.f);
    acc.y = fmaxf(acc.y + bv.y, 0.f);
    acc.z = fmaxf(acc.z + bv.z, 0.f);
    acc.w = fmaxf(acc.w + bv.w, 0.f);
    ((float4*)(g + (size_t)wid * F_HID))[lane] = acc;
}

// ---------------------------------------------------------------------------
// GEMM2: h2 = g @ W2   (N x 256) @ (256 x 40). One thread per output element;
// W2 staged in LDS (40 KB); g row reads are wave-broadcast float4s.
// ---------------------------------------------------------------------------

__global__ __launch_bounds__(256) void gemm2_kernel(const float* __restrict__ g,
                                                    const float* __restrict__ W2,
                                                    float* __restrict__ h2, int N) {
    __shared__ float Ws[F_HID * F_OUT];
    int tid = threadIdx.x;
    for (int i = tid; i < F_HID * F_OUT; i += 256) Ws[i] = W2[i];
    __syncthreads();
    int t = blockIdx.x * 256 + tid;
    if (t >= N * F_OUT) return;
    int r = t / F_OUT;
    int j = t - r * F_OUT;
    const float4* gr = (const float4*)(g + (size_t)r * F_HID);
    float acc = 0.f;
#pragma unroll 4
    for (int k4 = 0; k4 < F_HID / 4; ++k4) {
        float4 v = gr[k4];
        int k = k4 * 4;
        acc = fmaf(v.x, Ws[(k + 0) * F_OUT + j], acc);
        acc = fmaf(v.y, Ws[(k + 1) * F_OUT + j], acc);
        acc = fmaf(v.z, Ws[(k + 2) * F_OUT + j], acc);
        acc = fmaf(v.w, Ws[(k + 3) * F_OUT + j], acc);
    }
    h2[t] = acc;
}

// ---------------------------------------------------------------------------
// Propagate layer 2 (F=40) + bias, then fused log_softmax. One wave per row,
// lanes 0..39 = classes; width-64 shuffle reductions for max / sum(exp).
// Writes both outputs: final at [0, N*40), log_softmax at [N*40, 2*N*40).
// ---------------------------------------------------------------------------

__global__ __launch_bounds__(256) void prop2_kernel(const float* __restrict__ h2,
                                                    const float* __restrict__ b2,
                                                    const float* __restrict__ dinv,
                                                    const int* __restrict__ rowptr,
                                                    const int* __restrict__ col_s,
                                                    const float* __restrict__ norm_s,
                                                    float* __restrict__ out, int N) {
    int wid  = (blockIdx.x * blockDim.x + threadIdx.x) >> 6;
    int lane = threadIdx.x & 63;
    if (wid >= N) return;
    float di = dinv[wid];
    float sn = di * di;
    float acc = 0.f;
    if (lane < F_OUT) acc = sn * h2[(size_t)wid * F_OUT + lane];
    int e0 = rowptr[wid], e1 = rowptr[wid + 1];
    for (int e = e0; e < e1; ++e) {
        int   c = col_s[e];
        float w = norm_s[e];
        if (lane < F_OUT) acc = fmaf(w, h2[(size_t)c * F_OUT + lane], acc);
    }
    if (lane < F_OUT) acc += b2[lane];

    float a = (lane < F_OUT) ? acc : -INFINITY;
    float m = a;
#pragma unroll
    for (int o = 32; o; o >>= 1) m = fmaxf(m, __shfl_xor(m, o, 64));
    float ex = (lane < F_OUT) ? expf(acc - m) : 0.f;
    float s = ex;
#pragma unroll
    for (int o = 32; o; o >>= 1) s += __shfl_xor(s, o, 64);
    if (lane < F_OUT) {
        size_t base = (size_t)wid * F_OUT + lane;
        out[base] = acc;
        out[(size_t)N * F_OUT + base] = acc - m - logf(s);
    }
}

// ---------------------------------------------------------------------------
// Launch
// ---------------------------------------------------------------------------

extern "C" void kernel_launch(void* const* d_in, const int* in_sizes, int n_in,
                              void* d_out, int out_size, void* d_ws, size_t ws_size,
                              hipStream_t stream) {
    const float* x  = (const float*)d_in[0];
    const int*   ei = (const int*)d_in[1];   // (2, E) int32 flat
    const float* W1 = (const float*)d_in[2];
    const float* b1 = (const float*)d_in[3];
    const float* W2 = (const float*)d_in[4];
    const float* b2 = (const float*)d_in[5];
    float* out = (float*)d_out;

    const int N = in_sizes[0] / F_IN;
    const int E = in_sizes[1] / 2;
    const int* row = ei;
    const int* col = ei + E;

    // Workspace carve-out (256B aligned). Total ~= 232 MB.
    char* p = (char*)d_ws;
    auto alloc = [&](size_t bytes) -> char* {
        char* q = p;
        p += (bytes + 255) & ~(size_t)255;
        return q;
    };
    int*   cnt_row = (int*)alloc((size_t)N * 4);
    int*   cnt_col = (int*)alloc((size_t)N * 4);
    int*   rowptr  = (int*)alloc((size_t)(N + 1) * 4);
    int*   cursor  = (int*)alloc((size_t)N * 4);
    float* dinv    = (float*)alloc((size_t)N * 4);
    int*   col_s   = (int*)alloc((size_t)E * 4);
    float* norm_s  = (float*)alloc((size_t)E * 4);
    float* h       = (float*)alloc((size_t)N * F_HID * 4);
    float* g       = (float*)alloc((size_t)N * F_HID * 4);
    float* h2      = (float*)alloc((size_t)N * F_OUT * 4);

    hipMemsetAsync(cnt_row, 0, (size_t)N * 4, stream);
    hipMemsetAsync(cnt_col, 0, (size_t)N * 4, stream);

    count_kernel<<<(E + 255) / 256, 256, 0, stream>>>(row, col, cnt_row, cnt_col, E);
    dinv_kernel<<<(N + 255) / 256, 256, 0, stream>>>(cnt_col, dinv, N);
    scan_kernel<<<1, 1024, 0, stream>>>(cnt_row, rowptr, cursor, N);
    scatter_kernel<<<(E + 255) / 256, 256, 0, stream>>>(row, col, dinv, cursor, col_s, norm_s, E);

    dim3 g1(F_HID / 64, (N + 63) / 64);
    gemm1_kernel<<<g1, 256, 0, stream>>>(x, W1, h, N);

    prop1_kernel<<<(N + 3) / 4, 256, 0, stream>>>(h, b1, dinv, rowptr, col_s, norm_s, g, N);

    gemm2_kernel<<<((size_t)N * F_OUT + 255) / 256, 256, 0, stream>>>(g, W2, h2, N);

    prop2_kernel<<<(N + 3) / 4, 256, 0, stream>>>(h2, b2, dinv, rowptr, col_s, norm_s, out, N);
}

// Round 2
// 1691.923 us; speedup vs baseline: 1.2904x; 1.2904x over previous
//
#include <hip/hip_runtime.h>
#include <cstdint>
#include <cstddef>

#define F_IN  512
#define F_HID 256
#define F_OUT 40
#define F_OUTP 48   // padded to 3x16 MFMA tiles

typedef short  bf16x8 __attribute__((ext_vector_type(8)));
typedef float  f32x4  __attribute__((ext_vector_type(4)));

__device__ __forceinline__ ushort f2b(float f) {   // fp32 -> bf16 RNE
    uint u = __float_as_uint(f);
    return (ushort)((u + 0x7FFFu + ((u >> 16) & 1u)) >> 16);
}
__device__ __forceinline__ uint pack2(float a, float b) {
    return (uint)f2b(a) | ((uint)f2b(b) << 16);
}
__device__ __forceinline__ float b2f(ushort u) {
    return __uint_as_float(((uint)u) << 16);
}

// ---------------------------------------------------------------------------
// Graph preprocessing (unchanged from round 1 — correctness anchored).
// ---------------------------------------------------------------------------

__global__ void count_kernel(const int* __restrict__ row, const int* __restrict__ col,
                             int* __restrict__ cnt_row, int* __restrict__ cnt_col, int E) {
    int e = blockIdx.x * blockDim.x + threadIdx.x;
    if (e < E) {
        atomicAdd(&cnt_row[row[e]], 1);
        atomicAdd(&cnt_col[col[e]], 1);
    }
}

__global__ void dinv_kernel(const int* __restrict__ cnt_col, float* __restrict__ dinv, int N) {
    int i = blockIdx.x * blockDim.x + threadIdx.x;
    if (i < N) dinv[i] = rsqrtf((float)(cnt_col[i] + 1));
}

__global__ __launch_bounds__(1024) void scan_kernel(const int* __restrict__ cnt,
                                                    int* __restrict__ rowptr,
                                                    int* __restrict__ cursor, int N) {
    __shared__ int sums[1024];
    int tid = threadIdx.x;
    int chunk = (N + 1023) >> 10;
    int s0 = tid * chunk;
    int s1 = s0 + chunk;
    if (s0 > N) s0 = N;
    if (s1 > N) s1 = N;
    int sum = 0;
    for (int i = s0; i < s1; ++i) sum += cnt[i];
    sums[tid] = sum;
    __syncthreads();
    for (int off = 1; off < 1024; off <<= 1) {
        int v = (tid >= off) ? sums[tid - off] : 0;
        __syncthreads();
        sums[tid] += v;
        __syncthreads();
    }
    int base = (tid > 0) ? sums[tid - 1] : 0;
    for (int i = s0; i < s1; ++i) {
        rowptr[i] = base;
        cursor[i] = base;
        base += cnt[i];
    }
    if (tid == 0) rowptr[N] = sums[1023];
}

__global__ void scatter_kernel(const int* __restrict__ row, const int* __restrict__ col,
                               const float* __restrict__ dinv, int* __restrict__ cursor,
                               int* __restrict__ col_s, float* __restrict__ norm_s, int E) {
    int e = blockIdx.x * blockDim.x + threadIdx.x;
    if (e < E) {
        int r = row[e];
        int c = col[e];
        int pos = atomicAdd(&cursor[r], 1);
        col_s[pos]  = c;
        norm_s[pos] = dinv[r] * dinv[c];
    }
}

// ---------------------------------------------------------------------------
// Weight prep: W1T [256][512] bf16 (= W1^T), W2T [48][256] bf16 (= W2^T, rows
// 40..47 zero). Tiny (~140k elems); re-done every call.
// ---------------------------------------------------------------------------

__global__ void prep_weights(const float* __restrict__ W1, const float* __restrict__ W2,
                             ushort* __restrict__ W1T, ushort* __restrict__ W2T) {
    int t = blockIdx.x * blockDim.x + threadIdx.x;
    if (t < F_HID * F_IN) {                      // W1T[n][k] = W1[k][n]
        int n = t >> 9, k = t & 511;
        W1T[t] = f2b(W1[(size_t)k * F_HID + n]);
        return;
    }
    int u = t - F_HID * F_IN;
    if (u < F_OUTP * F_HID) {                    // W2T[n][k] = W2[k][n] (pad n>=40 with 0)
        int n = u >> 8, k = u & 255;
        W2T[u] = f2b((n < F_OUT) ? W2[(size_t)k * F_OUT + n] : 0.f);
    }
}

// ---------------------------------------------------------------------------
// GEMM1 (MFMA bf16): h[M,256] = x[M,512] @ W1.  BM=64, BN=256, BK=32.
// 4 waves; wave w owns n-range [w*64, w*64+64). x converted fp32->bf16 during
// LDS staging (x read once). LDS rows padded to 40 bf16 (80 B = 16 B aligned,
// 2-way-max bank aliasing on b128 frag reads).
// ---------------------------------------------------------------------------

#define G1_LDK 40

__global__ __launch_bounds__(256) void gemm1_mfma(const float* __restrict__ A,
                                                  const ushort* __restrict__ BT,  // W1T[256][512]
                                                  ushort* __restrict__ C,         // h bf16 [M,256]
                                                  int M) {
    __shared__ ushort As[64 * G1_LDK];
    __shared__ ushort Bs[256 * G1_LDK];
    const int tid  = threadIdx.x;
    const int bm   = blockIdx.x * 64;
    const int wave = tid >> 6;
    const int lane = tid & 63;
    const int quad = lane >> 4;
    const int l16  = lane & 15;

    f32x4 acc[4][4] = {};   // [mt][nt]

    // staging assignments
    const int ar = tid >> 2;            // A: row 0..63
    const int ac = (tid & 3) * 8;       //    col chunk 0,8,16,24

    for (int k0 = 0; k0 < F_IN; k0 += 32) {
        // ---- stage A (64x32 fp32 -> bf16), 8 elems/thread ----
        {
            int gr = bm + ar;
            float4 v0 = make_float4(0.f, 0.f, 0.f, 0.f), v1 = v0;
            if (gr < M) {
                const float* ap = A + (size_t)gr * F_IN + k0 + ac;
                v0 = *(const float4*)(ap);
                v1 = *(const float4*)(ap + 4);
            }
            uint4 w;
            w.x = pack2(v0.x, v0.y);
            w.y = pack2(v0.z, v0.w);
            w.z = pack2(v1.x, v1.y);
            w.w = pack2(v1.z, v1.w);
            *(uint4*)&As[ar * G1_LDK + ac] = w;
        }
        // ---- stage B (256x32 bf16), 4 x 16B/thread ----
#pragma unroll
        for (int p = 0; p < 4; ++p) {
            int idx = tid + p * 256;
            int r = idx >> 2;
            int c = (idx & 3) * 8;
            uint4 v = *(const uint4*)(BT + (size_t)r * F_IN + k0 + c);
            *(uint4*)&Bs[r * G1_LDK + c] = v;
        }
        __syncthreads();

        bf16x8 af[4], bfr[4];
#pragma unroll
        for (int mt = 0; mt < 4; ++mt)
            af[mt] = *(bf16x8*)&As[(mt * 16 + l16) * G1_LDK + quad * 8];
#pragma unroll
        for (int nt = 0; nt < 4; ++nt)
            bfr[nt] = *(bf16x8*)&Bs[(wave * 64 + nt * 16 + l16) * G1_LDK + quad * 8];
#pragma unroll
        for (int mt = 0; mt < 4; ++mt)
#pragma unroll
            for (int nt = 0; nt < 4; ++nt)
                acc[mt][nt] = __builtin_amdgcn_mfma_f32_16x16x32_bf16(af[mt], bfr[nt],
                                                                     acc[mt][nt], 0, 0, 0);
        __syncthreads();
    }

    // epilogue: C/D layout col=lane&15, row=quad*4+reg
#pragma unroll
    for (int mt = 0; mt < 4; ++mt) {
#pragma unroll
        for (int i = 0; i < 4; ++i) {
            int row = bm + mt * 16 + quad * 4 + i;
            if (row < M) {
#pragma unroll
                for (int nt = 0; nt < 4; ++nt) {
                    int col = wave * 64 + nt * 16 + l16;
                    C[(size_t)row * F_HID + col] = f2b(acc[mt][nt][i]);
                }
            }
        }
    }
}

// ---------------------------------------------------------------------------
// Propagate layer 1 (F=256, bf16 in/out) + bias + ReLU. One wave per row;
// lane holds 4 features (8 B) -> each neighbor gather is a coalesced 512 B read.
// ---------------------------------------------------------------------------

__global__ __launch_bounds__(256) void prop1_kernel(const ushort* __restrict__ h,
                                                    const float* __restrict__ b1,
                                                    const float* __restrict__ dinv,
                                                    const int* __restrict__ rowptr,
                                                    const int* __restrict__ col_s,
                                                    const float* __restrict__ norm_s,
                                                    ushort* __restrict__ g, int N) {
    int wid  = (blockIdx.x * blockDim.x + threadIdx.x) >> 6;
    int lane = threadIdx.x & 63;
    if (wid >= N) return;
    float di = dinv[wid];
    float sn = di * di;
    ushort4 sv = ((const ushort4*)(h + (size_t)wid * F_HID))[lane];
    float ax = sn * b2f(sv.x), ay = sn * b2f(sv.y), az = sn * b2f(sv.z), aw = sn * b2f(sv.w);
    int e0 = rowptr[wid], e1 = rowptr[wid + 1];
    for (int e = e0; e < e1; ++e) {
        int   c = col_s[e];
        float w = norm_s[e];
        ushort4 v = ((const ushort4*)(h + (size_t)c * F_HID))[lane];
        ax = fmaf(w, b2f(v.x), ax);
        ay = fmaf(w, b2f(v.y), ay);
        az = fmaf(w, b2f(v.z), az);
        aw = fmaf(w, b2f(v.w), aw);
    }
    float4 bv = ((const float4*)b1)[lane];
    ax = fmaxf(ax + bv.x, 0.f);
    ay = fmaxf(ay + bv.y, 0.f);
    az = fmaxf(az + bv.z, 0.f);
    aw = fmaxf(aw + bv.w, 0.f);
    ushort4 o;
    o.x = f2b(ax); o.y = f2b(ay); o.z = f2b(az); o.w = f2b(aw);
    ((ushort4*)(g + (size_t)wid * F_HID))[lane] = o;
}

// ---------------------------------------------------------------------------
// GEMM2 (MFMA bf16): h2[M,40] = g[M,256] @ W2.  BM=64, N padded to 48, full
// K=256 staged in LDS once per block (no K staging loop). Wave w owns m-rows
// [w*16, w*16+16); 3 n-tiles each.
// ---------------------------------------------------------------------------

#define G2_LDK 264

__global__ __launch_bounds__(256) void gemm2_mfma(const ushort* __restrict__ G,   // g bf16 [M,256]
                                                  const ushort* __restrict__ BT,  // W2T[48][256]
                                                  ushort* __restrict__ H2,        // bf16 [M,40]
                                                  int M) {
    __shared__ ushort As[64 * G2_LDK];
    __shared__ ushort Bs[F_OUTP * G2_LDK];
    const int tid  = threadIdx.x;
    const int bm   = blockIdx.x * 64;
    const int wave = tid >> 6;
    const int lane = tid & 63;
    const int quad = lane >> 4;
    const int l16  = lane & 15;

    // stage A: 64 rows x 256 bf16 = 2048 chunks of 8 -> 8/thread
#pragma unroll
    for (int p = 0; p < 8; ++p) {
        int idx = tid + p * 256;
        int r = idx >> 5;
        int c = (idx & 31) * 8;
        uint4 v = make_uint4(0, 0, 0, 0);
        int gr = bm + r;
        if (gr < M) v = *(const uint4*)(G + (size_t)gr * F_HID + c);
        *(uint4*)&As[r * G2_LDK + c] = v;
    }
    // stage B: 48 x 256 = 1536 chunks -> 6/thread
#pragma unroll
    for (int p = 0; p < 6; ++p) {
        int idx = tid + p * 256;
        int r = idx >> 5;
        int c = (idx & 31) * 8;
        uint4 v = *(const uint4*)(BT + (size_t)r * F_HID + c);
        *(uint4*)&Bs[r * G2_LDK + c] = v;
    }
    __syncthreads();

    f32x4 acc[3] = {};
#pragma unroll
    for (int ks = 0; ks < F_HID / 32; ++ks) {
        bf16x8 a = *(bf16x8*)&As[(wave * 16 + l16) * G2_LDK + ks * 32 + quad * 8];
#pragma unroll
        for (int nt = 0; nt < 3; ++nt) {
            bf16x8 b = *(bf16x8*)&Bs[(nt * 16 + l16) * G2_LDK + ks * 32 + quad * 8];
            acc[nt] = __builtin_amdgcn_mfma_f32_16x16x32_bf16(a, b, acc[nt], 0, 0, 0);
        }
    }

#pragma unroll
    for (int i = 0; i < 4; ++i) {
        int row = bm + wave * 16 + quad * 4 + i;
        if (row < M) {
#pragma unroll
            for (int nt = 0; nt < 3; ++nt) {
                int col = nt * 16 + l16;
                if (col < F_OUT)
                    H2[(size_t)row * F_OUT + col] = f2b(acc[nt][i]);
            }
        }
    }
}

// ---------------------------------------------------------------------------
// Propagate layer 2 (F=40, bf16 in) + bias + fused log_softmax (fp32 out).
// ---------------------------------------------------------------------------

__global__ __launch_bounds__(256) void prop2_kernel(const ushort* __restrict__ h2,
                                                    const float* __restrict__ b2,
                                                    const float* __restrict__ dinv,
                                                    const int* __restrict__ rowptr,
                                                    const int* __restrict__ col_s,
                                                    const float* __restrict__ norm_s,
                                                    float* __restrict__ out, int N) {
    int wid  = (blockIdx.x * blockDim.x + threadIdx.x) >> 6;
    int lane = threadIdx.x & 63;
    if (wid >= N) return;
    float di = dinv[wid];
    float sn = di * di;
    float acc = 0.f;
    if (lane < F_OUT) acc = sn * b2f(h2[(size_t)wid * F_OUT + lane]);
    int e0 = rowptr[wid], e1 = rowptr[wid + 1];
    for (int e = e0; e < e1; ++e) {
        int   c = col_s[e];
        float w = norm_s[e];
        if (lane < F_OUT) acc = fmaf(w, b2f(h2[(size_t)c * F_OUT + lane]), acc);
    }
    if (lane < F_OUT) acc += b2[lane];

    float a = (lane < F_OUT) ? acc : -INFINITY;
    float m = a;
#pragma unroll
    for (int o = 32; o; o >>= 1) m = fmaxf(m, __shfl_xor(m, o, 64));
    float ex = (lane < F_OUT) ? expf(acc - m) : 0.f;
    float s = ex;
#pragma unroll
    for (int o = 32; o; o >>= 1) s += __shfl_xor(s, o, 64);
    if (lane < F_OUT) {
        size_t base = (size_t)wid * F_OUT + lane;
        out[base] = acc;
        out[(size_t)N * F_OUT + base] = acc - m - logf(s);
    }
}

// ---------------------------------------------------------------------------
// Launch
// ---------------------------------------------------------------------------

extern "C" void kernel_launch(void* const* d_in, const int* in_sizes, int n_in,
                              void* d_out, int out_size, void* d_ws, size_t ws_size,
                              hipStream_t stream) {
    const float* x  = (const float*)d_in[0];
    const int*   ei = (const int*)d_in[1];
    const float* W1 = (const float*)d_in[2];
    const float* b1 = (const float*)d_in[3];
    const float* W2 = (const float*)d_in[4];
    const float* b2 = (const float*)d_in[5];
    float* out = (float*)d_out;

    const int N = in_sizes[0] / F_IN;
    const int E = in_sizes[1] / 2;
    const int* row = ei;
    const int* col = ei + E;

    char* p = (char*)d_ws;
    auto alloc = [&](size_t bytes) -> char* {
        char* q = p;
        p += (bytes + 255) & ~(size_t)255;
        return q;
    };
    int*    cnt_row = (int*)alloc((size_t)N * 4);
    int*    cnt_col = (int*)alloc((size_t)N * 4);
    int*    rowptr  = (int*)alloc((size_t)(N + 1) * 4);
    int*    cursor  = (int*)alloc((size_t)N * 4);
    float*  dinv    = (float*)alloc((size_t)N * 4);
    int*    col_s   = (int*)alloc((size_t)E * 4);
    float*  norm_s  = (float*)alloc((size_t)E * 4);
    ushort* W1T     = (ushort*)alloc((size_t)F_HID * F_IN * 2);
    ushort* W2T     = (ushort*)alloc((size_t)F_OUTP * F_HID * 2);
    ushort* h       = (ushort*)alloc((size_t)N * F_HID * 2);
    ushort* g       = (ushort*)alloc((size_t)N * F_HID * 2);
    ushort* h2      = (ushort*)alloc((size_t)N * F_OUT * 2);

    hipMemsetAsync(cnt_row, 0, (size_t)N * 4, stream);
    hipMemsetAsync(cnt_col, 0, (size_t)N * 4, stream);

    count_kernel<<<(E + 255) / 256, 256, 0, stream>>>(row, col, cnt_row, cnt_col, E);
    dinv_kernel<<<(N + 255) / 256, 256, 0, stream>>>(cnt_col, dinv, N);
    scan_kernel<<<1, 1024, 0, stream>>>(cnt_row, rowptr, cursor, N);
    scatter_kernel<<<(E + 255) / 256, 256, 0, stream>>>(row, col, dinv, cursor, col_s, norm_s, E);

    int prep_total = F_HID * F_IN + F_OUTP * F_HID;
    prep_weights<<<(prep_total + 255) / 256, 256, 0, stream>>>(W1, W2, W1T, W2T);

    gemm1_mfma<<<(N + 63) / 64, 256, 0, stream>>>(x, W1T, h, N);
    prop1_kernel<<<(N + 3) / 4, 256, 0, stream>>>(h, b1, dinv, rowptr, col_s, norm_s, g, N);
    gemm2_mfma<<<(N + 63) / 64, 256, 0, stream>>>(g, W2T, h2, N);
    prop2_kernel<<<(N + 3) / 4, 256, 0, stream>>>(h2, b2, dinv, rowptr, col_s, norm_s, out, N);
}

// Round 3
// 1280.563 us; speedup vs baseline: 1.7050x; 1.3212x over previous
//
#include <hip/hip_runtime.h>
#include <cstdint>
#include <cstddef>

#define F_IN  512
#define F_HID 256
#define F_OUT 40
#define F_OUTP 48   // padded to 3x16 MFMA tiles

typedef short  bf16x8 __attribute__((ext_vector_type(8)));
typedef float  f32x4  __attribute__((ext_vector_type(4)));

__device__ __forceinline__ ushort f2b(float f) {   // fp32 -> bf16 RNE
    uint u = __float_as_uint(f);
    return (ushort)((u + 0x7FFFu + ((u >> 16) & 1u)) >> 16);
}
__device__ __forceinline__ uint pack2(float a, float b) {
    return (uint)f2b(a) | ((uint)f2b(b) << 16);
}
__device__ __forceinline__ float b2f(ushort u) {
    return __uint_as_float(((uint)u) << 16);
}

// ---------------------------------------------------------------------------
// Graph preprocessing
// ---------------------------------------------------------------------------

__global__ void count_kernel(const int* __restrict__ row, const int* __restrict__ col,
                             int* __restrict__ cnt_row, int* __restrict__ cnt_col, int E) {
    int e = blockIdx.x * blockDim.x + threadIdx.x;
    if (e < E) {
        atomicAdd(&cnt_row[row[e]], 1);
        atomicAdd(&cnt_col[col[e]], 1);
    }
}

__global__ void dinv_kernel(const int* __restrict__ cnt_col, float* __restrict__ dinv, int N) {
    int i = blockIdx.x * blockDim.x + threadIdx.x;
    if (i < N) dinv[i] = rsqrtf((float)(cnt_col[i] + 1));
}

__global__ __launch_bounds__(1024) void scan_kernel(const int* __restrict__ cnt,
                                                    int* __restrict__ rowptr,
                                                    int* __restrict__ cursor, int N) {
    __shared__ int sums[1024];
    int tid = threadIdx.x;
    int chunk = (N + 1023) >> 10;
    int s0 = tid * chunk;
    int s1 = s0 + chunk;
    if (s0 > N) s0 = N;
    if (s1 > N) s1 = N;
    int sum = 0;
    for (int i = s0; i < s1; ++i) sum += cnt[i];
    sums[tid] = sum;
    __syncthreads();
    for (int off = 1; off < 1024; off <<= 1) {
        int v = (tid >= off) ? sums[tid - off] : 0;
        __syncthreads();
        sums[tid] += v;
        __syncthreads();
    }
    int base = (tid > 0) ? sums[tid - 1] : 0;
    for (int i = s0; i < s1; ++i) {
        rowptr[i] = base;
        cursor[i] = base;
        base += cnt[i];
    }
    if (tid == 0) rowptr[N] = sums[1023];
}

// One 8 B store per edge: (col, norm-bits) packed.
__global__ void scatter_kernel(const int* __restrict__ row, const int* __restrict__ col,
                               const float* __restrict__ dinv, int* __restrict__ cursor,
                               uint2* __restrict__ edge_s, int E) {
    int e = blockIdx.x * blockDim.x + threadIdx.x;
    if (e < E) {
        int r = row[e];
        int c = col[e];
        int pos = atomicAdd(&cursor[r], 1);
        uint2 v;
        v.x = (uint)c;
        v.y = __float_as_uint(dinv[r] * dinv[c]);
        edge_s[pos] = v;
    }
}

// ---------------------------------------------------------------------------
// Weight prep: W1T [256][512] bf16 (= W1^T), W2T [48][256] bf16 (rows 40..47 = 0).
// ---------------------------------------------------------------------------

__global__ void prep_weights(const float* __restrict__ W1, const float* __restrict__ W2,
                             ushort* __restrict__ W1T, ushort* __restrict__ W2T) {
    int t = blockIdx.x * blockDim.x + threadIdx.x;
    if (t < F_HID * F_IN) {
        int n = t >> 9, k = t & 511;
        W1T[t] = f2b(W1[(size_t)k * F_HID + n]);
        return;
    }
    int u = t - F_HID * F_IN;
    if (u < F_OUTP * F_HID) {
        int n = u >> 8, k = u & 255;
        W2T[u] = f2b((n < F_OUT) ? W2[(size_t)k * F_OUT + n] : 0.f);
    }
}

// ---------------------------------------------------------------------------
// GEMM1 (MFMA bf16): h[M,256] = x[M,512] @ W1.  BM=64, BN=256, BK=32.
// ---------------------------------------------------------------------------

#define G1_LDK 40

__global__ __launch_bounds__(256) void gemm1_mfma(const float* __restrict__ A,
                                                  const ushort* __restrict__ BT,
                                                  ushort* __restrict__ C, int M) {
    __shared__ ushort As[64 * G1_LDK];
    __shared__ ushort Bs[256 * G1_LDK];
    const int tid  = threadIdx.x;
    const int bm   = blockIdx.x * 64;
    const int wave = tid >> 6;
    const int lane = tid & 63;
    const int quad = lane >> 4;
    const int l16  = lane & 15;

    f32x4 acc[4][4] = {};

    const int ar = tid >> 2;
    const int ac = (tid & 3) * 8;

    for (int k0 = 0; k0 < F_IN; k0 += 32) {
        {
            int gr = bm + ar;
            float4 v0 = make_float4(0.f, 0.f, 0.f, 0.f), v1 = v0;
            if (gr < M) {
                const float* ap = A + (size_t)gr * F_IN + k0 + ac;
                v0 = *(const float4*)(ap);
                v1 = *(const float4*)(ap + 4);
            }
            uint4 w;
            w.x = pack2(v0.x, v0.y);
            w.y = pack2(v0.z, v0.w);
            w.z = pack2(v1.x, v1.y);
            w.w = pack2(v1.z, v1.w);
            *(uint4*)&As[ar * G1_LDK + ac] = w;
        }
#pragma unroll
        for (int p = 0; p < 4; ++p) {
            int idx = tid + p * 256;
            int r = idx >> 2;
            int c = (idx & 3) * 8;
            uint4 v = *(const uint4*)(BT + (size_t)r * F_IN + k0 + c);
            *(uint4*)&Bs[r * G1_LDK + c] = v;
        }
        __syncthreads();

        bf16x8 af[4], bfr[4];
#pragma unroll
        for (int mt = 0; mt < 4; ++mt)
            af[mt] = *(bf16x8*)&As[(mt * 16 + l16) * G1_LDK + quad * 8];
#pragma unroll
        for (int nt = 0; nt < 4; ++nt)
            bfr[nt] = *(bf16x8*)&Bs[(wave * 64 + nt * 16 + l16) * G1_LDK + quad * 8];
#pragma unroll
        for (int mt = 0; mt < 4; ++mt)
#pragma unroll
            for (int nt = 0; nt < 4; ++nt)
                acc[mt][nt] = __builtin_amdgcn_mfma_f32_16x16x32_bf16(af[mt], bfr[nt],
                                                                     acc[mt][nt], 0, 0, 0);
        __syncthreads();
    }

#pragma unroll
    for (int mt = 0; mt < 4; ++mt) {
#pragma unroll
        for (int i = 0; i < 4; ++i) {
            int row = bm + mt * 16 + quad * 4 + i;
            if (row < M) {
#pragma unroll
                for (int nt = 0; nt < 4; ++nt) {
                    int col = wave * 64 + nt * 16 + l16;
                    C[(size_t)row * F_HID + col] = f2b(acc[mt][nt][i]);
                }
            }
        }
    }
}

// ---------------------------------------------------------------------------
// Propagate layer 1 (F=256, bf16) + bias + ReLU. One wave per row; edge loop
// unrolled x8 so 8 gathers are in flight before the accumulate drains them.
// ---------------------------------------------------------------------------

#define P1U 8

__global__ __launch_bounds__(256) void prop1_kernel(const ushort* __restrict__ h,
                                                    const float* __restrict__ b1,
                                                    const float* __restrict__ dinv,
                                                    const int* __restrict__ rowptr,
                                                    const uint2* __restrict__ edge_s,
                                                    ushort* __restrict__ g, int N) {
    int wid  = (blockIdx.x * blockDim.x + threadIdx.x) >> 6;
    int lane = threadIdx.x & 63;
    if (wid >= N) return;
    float di = dinv[wid];
    float sn = di * di;
    ushort4 sv = ((const ushort4*)(h + (size_t)wid * F_HID))[lane];
    float ax = sn * b2f(sv.x), ay = sn * b2f(sv.y), az = sn * b2f(sv.z), aw = sn * b2f(sv.w);
    int e0 = rowptr[wid], e1 = rowptr[wid + 1];
    int e = e0;
    for (; e + P1U <= e1; e += P1U) {
        ushort4 v[P1U];
        float   w[P1U];
#pragma unroll
        for (int u = 0; u < P1U; ++u) {
            uint2 ev = edge_s[e + u];
            w[u] = __uint_as_float(ev.y);
            v[u] = ((const ushort4*)(h + (size_t)ev.x * F_HID))[lane];
        }
#pragma unroll
        for (int u = 0; u < P1U; ++u) {
            ax = fmaf(w[u], b2f(v[u].x), ax);
            ay = fmaf(w[u], b2f(v[u].y), ay);
            az = fmaf(w[u], b2f(v[u].z), az);
            aw = fmaf(w[u], b2f(v[u].w), aw);
        }
    }
    for (; e < e1; ++e) {
        uint2 ev = edge_s[e];
        float w = __uint_as_float(ev.y);
        ushort4 v = ((const ushort4*)(h + (size_t)ev.x * F_HID))[lane];
        ax = fmaf(w, b2f(v.x), ax);
        ay = fmaf(w, b2f(v.y), ay);
        az = fmaf(w, b2f(v.z), az);
        aw = fmaf(w, b2f(v.w), aw);
    }
    float4 bv = ((const float4*)b1)[lane];
    ax = fmaxf(ax + bv.x, 0.f);
    ay = fmaxf(ay + bv.y, 0.f);
    az = fmaxf(az + bv.z, 0.f);
    aw = fmaxf(aw + bv.w, 0.f);
    ushort4 o;
    o.x = f2b(ax); o.y = f2b(ay); o.z = f2b(az); o.w = f2b(aw);
    ((ushort4*)(g + (size_t)wid * F_HID))[lane] = o;
}

// ---------------------------------------------------------------------------
// GEMM2 (MFMA bf16): h2[M,40] = g[M,256] @ W2, K fully LDS-staged.
// ---------------------------------------------------------------------------

#define G2_LDK 264

__global__ __launch_bounds__(256) void gemm2_mfma(const ushort* __restrict__ G,
                                                  const ushort* __restrict__ BT,
                                                  ushort* __restrict__ H2, int M) {
    __shared__ ushort As[64 * G2_LDK];
    __shared__ ushort Bs[F_OUTP * G2_LDK];
    const int tid  = threadIdx.x;
    const int bm   = blockIdx.x * 64;
    const int wave = tid >> 6;
    const int lane = tid & 63;
    const int quad = lane >> 4;
    const int l16  = lane & 15;

#pragma unroll
    for (int p = 0; p < 8; ++p) {
        int idx = tid + p * 256;
        int r = idx >> 5;
        int c = (idx & 31) * 8;
        uint4 v = make_uint4(0, 0, 0, 0);
        int gr = bm + r;
        if (gr < M) v = *(const uint4*)(G + (size_t)gr * F_HID + c);
        *(uint4*)&As[r * G2_LDK + c] = v;
    }
#pragma unroll
    for (int p = 0; p < 6; ++p) {
        int idx = tid + p * 256;
        int r = idx >> 5;
        int c = (idx & 31) * 8;
        uint4 v = *(const uint4*)(BT + (size_t)r * F_HID + c);
        *(uint4*)&Bs[r * G2_LDK + c] = v;
    }
    __syncthreads();

    f32x4 acc[3] = {};
#pragma unroll
    for (int ks = 0; ks < F_HID / 32; ++ks) {
        bf16x8 a = *(bf16x8*)&As[(wave * 16 + l16) * G2_LDK + ks * 32 + quad * 8];
#pragma unroll
        for (int nt = 0; nt < 3; ++nt) {
            bf16x8 b = *(bf16x8*)&Bs[(nt * 16 + l16) * G2_LDK + ks * 32 + quad * 8];
            acc[nt] = __builtin_amdgcn_mfma_f32_16x16x32_bf16(a, b, acc[nt], 0, 0, 0);
        }
    }

#pragma unroll
    for (int i = 0; i < 4; ++i) {
        int row = bm + wave * 16 + quad * 4 + i;
        if (row < M) {
#pragma unroll
            for (int nt = 0; nt < 3; ++nt) {
                int col = nt * 16 + l16;
                if (col < F_OUT)
                    H2[(size_t)row * F_OUT + col] = f2b(acc[nt][i]);
            }
        }
    }
}

// ---------------------------------------------------------------------------
// Propagate layer 2 (F=40, bf16 in) + bias + fused log_softmax. Lanes >= 40
// read feature 0 (same cache lines) instead of diverging; edge loop unrolled x8.
// ---------------------------------------------------------------------------

#define P2U 8

__global__ __launch_bounds__(256) void prop2_kernel(const ushort* __restrict__ h2,
                                                    const float* __restrict__ b2,
                                                    const float* __restrict__ dinv,
                                                    const int* __restrict__ rowptr,
                                                    const uint2* __restrict__ edge_s,
                                                    float* __restrict__ out, int N) {
    int wid  = (blockIdx.x * blockDim.x + threadIdx.x) >> 6;
    int lane = threadIdx.x & 63;
    if (wid >= N) return;
    int li = (lane < F_OUT) ? lane : 0;   // clamp: no divergence, same lines
    float di = dinv[wid];
    float sn = di * di;
    float acc = sn * b2f(h2[(size_t)wid * F_OUT + li]);
    int e0 = rowptr[wid], e1 = rowptr[wid + 1];
    int e = e0;
    for (; e + P2U <= e1; e += P2U) {
        ushort v[P2U];
        float  w[P2U];
#pragma unroll
        for (int u = 0; u < P2U; ++u) {
            uint2 ev = edge_s[e + u];
            w[u] = __uint_as_float(ev.y);
            v[u] = h2[(size_t)ev.x * F_OUT + li];
        }
#pragma unroll
        for (int u = 0; u < P2U; ++u) acc = fmaf(w[u], b2f(v[u]), acc);
    }
    for (; e < e1; ++e) {
        uint2 ev = edge_s[e];
        acc = fmaf(__uint_as_float(ev.y), b2f(h2[(size_t)ev.x * F_OUT + li]), acc);
    }
    acc += b2[li];

    float a = (lane < F_OUT) ? acc : -INFINITY;
    float m = a;
#pragma unroll
    for (int o = 32; o; o >>= 1) m = fmaxf(m, __shfl_xor(m, o, 64));
    float ex = (lane < F_OUT) ? expf(acc - m) : 0.f;
    float s = ex;
#pragma unroll
    for (int o = 32; o; o >>= 1) s += __shfl_xor(s, o, 64);
    if (lane < F_OUT) {
        size_t base = (size_t)wid * F_OUT + lane;
        out[base] = acc;
        out[(size_t)N * F_OUT + base] = acc - m - logf(s);
    }
}

// ---------------------------------------------------------------------------
// Launch
// ---------------------------------------------------------------------------

extern "C" void kernel_launch(void* const* d_in, const int* in_sizes, int n_in,
                              void* d_out, int out_size, void* d_ws, size_t ws_size,
                              hipStream_t stream) {
    const float* x  = (const float*)d_in[0];
    const int*   ei = (const int*)d_in[1];
    const float* W1 = (const float*)d_in[2];
    const float* b1 = (const float*)d_in[3];
    const float* W2 = (const float*)d_in[4];
    const float* b2 = (const float*)d_in[5];
    float* out = (float*)d_out;

    const int N = in_sizes[0] / F_IN;
    const int E = in_sizes[1] / 2;
    const int* row = ei;
    const int* col = ei + E;

    char* p = (char*)d_ws;
    auto alloc = [&](size_t bytes) -> char* {
        char* q = p;
        p += (bytes + 255) & ~(size_t)255;
        return q;
    };
    int*    cnt_row = (int*)alloc((size_t)N * 4);
    int*    cnt_col = (int*)alloc((size_t)N * 4);
    int*    rowptr  = (int*)alloc((size_t)(N + 1) * 4);
    int*    cursor  = (int*)alloc((size_t)N * 4);
    float*  dinv    = (float*)alloc((size_t)N * 4);
    uint2*  edge_s  = (uint2*)alloc((size_t)E * 8);
    ushort* W1T     = (ushort*)alloc((size_t)F_HID * F_IN * 2);
    ushort* W2T     = (ushort*)alloc((size_t)F_OUTP * F_HID * 2);
    ushort* h       = (ushort*)alloc((size_t)N * F_HID * 2);
    ushort* g       = (ushort*)alloc((size_t)N * F_HID * 2);
    ushort* h2      = (ushort*)alloc((size_t)N * F_OUT * 2);

    hipMemsetAsync(cnt_row, 0, (size_t)N * 4, stream);
    hipMemsetAsync(cnt_col, 0, (size_t)N * 4, stream);

    count_kernel<<<(E + 255) / 256, 256, 0, stream>>>(row, col, cnt_row, cnt_col, E);
    dinv_kernel<<<(N + 255) / 256, 256, 0, stream>>>(cnt_col, dinv, N);
    scan_kernel<<<1, 1024, 0, stream>>>(cnt_row, rowptr, cursor, N);
    scatter_kernel<<<(E + 255) / 256, 256, 0, stream>>>(row, col, dinv, cursor, edge_s, E);

    int prep_total = F_HID * F_IN + F_OUTP * F_HID;
    prep_weights<<<(prep_total + 255) / 256, 256, 0, stream>>>(W1, W2, W1T, W2T);

    gemm1_mfma<<<(N + 63) / 64, 256, 0, stream>>>(x, W1T, h, N);
    prop1_kernel<<<(N + 3) / 4, 256, 0, stream>>>(h, b1, dinv, rowptr, edge_s, g, N);
    gemm2_mfma<<<(N + 63) / 64, 256, 0, stream>>>(g, W2T, h2, N);
    prop2_kernel<<<(N + 3) / 4, 256, 0, stream>>>(h2, b2, dinv, rowptr, edge_s, out, N);
}

// Round 4
// 1211.232 us; speedup vs baseline: 1.8026x; 1.0572x over previous
//
#include <hip/hip_runtime.h>
#include <cstdint>
#include <cstddef>

#define F_IN  512
#define F_HID 256
#define F_OUT 40
#define F_OUTP 48   // padded to 3x16 MFMA tiles

#define HBINS 16384        // 64 KB LDS histogram bins
#define HSLICES 36         // edge slices for hist pass

typedef short  bf16x8 __attribute__((ext_vector_type(8)));
typedef float  f32x4  __attribute__((ext_vector_type(4)));

__device__ __forceinline__ ushort f2b(float f) {   // fp32 -> bf16 RNE
    uint u = __float_as_uint(f);
    return (ushort)((u + 0x7FFFu + ((u >> 16) & 1u)) >> 16);
}
__device__ __forceinline__ uint pack2(float a, float b) {
    return (uint)f2b(a) | ((uint)f2b(b) << 16);
}
__device__ __forceinline__ float b2f(ushort u) {
    return __uint_as_float(((uint)u) << 16);
}

// ---------------------------------------------------------------------------
// Degree histogram WITHOUT global atomics: block (slice s, range r, array a)
// scans its edge slice, counts indices in [r*HBINS, r*HBINS+HBINS) into an LDS
// histogram, then writes the 64 KB partial to scratch non-atomically.
// ---------------------------------------------------------------------------

__global__ __launch_bounds__(1024) void hist_kernel(const int* __restrict__ ei,
                                                    int* __restrict__ part,
                                                    int E, int NR) {
    __shared__ int hist[HBINS];
    const int tid = threadIdx.x;
    const int s = blockIdx.x;
    const int r = blockIdx.y;
    const int a = blockIdx.z;
    const int* src = ei + (size_t)a * E;   // a=0: row, a=1: col
    const uint base = (uint)r * HBINS;

    for (int i = tid; i < HBINS; i += 1024) hist[i] = 0;
    __syncthreads();

    int elen  = (E + HSLICES - 1) / HSLICES;
    int start = s * elen;
    int end   = min(start + elen, E);
    for (int i = start + tid; i < end; i += 1024) {
        uint b = (uint)src[i] - base;
        if (b < HBINS) atomicAdd(&hist[b], 1);
    }
    __syncthreads();

    int* dst = part + ((size_t)(a * NR + r) * HSLICES + s) * HBINS;
    for (int i = tid; i < HBINS; i += 1024) dst[i] = hist[i];
}

// Sum the HSLICES partials per (array, node). a=0 -> cnt_row; a=1 -> dinv.
__global__ void hist_reduce(const int* __restrict__ part,
                            int* __restrict__ cnt_row,
                            float* __restrict__ dinv, int N, int NR) {
    int t = blockIdx.x * blockDim.x + threadIdx.x;
    if (t >= 2 * N) return;
    int a = (t >= N) ? 1 : 0;
    int i = t - a * N;
    int r = i >> 14;             // / HBINS
    int bin = i & (HBINS - 1);
    const int* p = part + ((size_t)(a * NR + r) * HSLICES) * HBINS + bin;
    int sum = 0;
#pragma unroll 4
    for (int s = 0; s < HSLICES; ++s) sum += p[(size_t)s * HBINS];
    if (a == 0) cnt_row[i] = sum;
    else        dinv[i] = rsqrtf((float)(sum + 1));
}

// ---------------------------------------------------------------------------
// Single-block exclusive scan of cnt_row -> rowptr[N+1]; cursor copy.
// ---------------------------------------------------------------------------

__global__ __launch_bounds__(1024) void scan_kernel(const int* __restrict__ cnt,
                                                    int* __restrict__ rowptr,
                                                    int* __restrict__ cursor, int N) {
    __shared__ int sums[1024];
    int tid = threadIdx.x;
    int chunk = (N + 1023) >> 10;
    int s0 = tid * chunk;
    int s1 = s0 + chunk;
    if (s0 > N) s0 = N;
    if (s1 > N) s1 = N;
    int sum = 0;
    for (int i = s0; i < s1; ++i) sum += cnt[i];
    sums[tid] = sum;
    __syncthreads();
    for (int off = 1; off < 1024; off <<= 1) {
        int v = (tid >= off) ? sums[tid - off] : 0;
        __syncthreads();
        sums[tid] += v;
        __syncthreads();
    }
    int base = (tid > 0) ? sums[tid - 1] : 0;
    for (int i = s0; i < s1; ++i) {
        rowptr[i] = base;
        cursor[i] = base;
        base += cnt[i];
    }
    if (tid == 0) rowptr[N] = sums[1023];
}

// One 8 B store per edge: (col, norm-bits) packed.
__global__ void scatter_kernel(const int* __restrict__ row, const int* __restrict__ col,
                               const float* __restrict__ dinv, int* __restrict__ cursor,
                               uint2* __restrict__ edge_s, int E) {
    int e = blockIdx.x * blockDim.x + threadIdx.x;
    if (e < E) {
        int r = row[e];
        int c = col[e];
        int pos = atomicAdd(&cursor[r], 1);
        uint2 v;
        v.x = (uint)c;
        v.y = __float_as_uint(dinv[r] * dinv[c]);
        edge_s[pos] = v;
    }
}

// ---------------------------------------------------------------------------
// Weight prep: W1T [256][512] bf16 (= W1^T), W2T [48][256] bf16 (rows 40..47=0).
// ---------------------------------------------------------------------------

__global__ void prep_weights(const float* __restrict__ W1, const float* __restrict__ W2,
                             ushort* __restrict__ W1T, ushort* __restrict__ W2T) {
    int t = blockIdx.x * blockDim.x + threadIdx.x;
    if (t < F_HID * F_IN) {
        int n = t >> 9, k = t & 511;
        W1T[t] = f2b(W1[(size_t)k * F_HID + n]);
        return;
    }
    int u = t - F_HID * F_IN;
    if (u < F_OUTP * F_HID) {
        int n = u >> 8, k = u & 255;
        W2T[u] = f2b((n < F_OUT) ? W2[(size_t)k * F_OUT + n] : 0.f);
    }
}

// ---------------------------------------------------------------------------
// GEMM1 (MFMA bf16): h[M,256] = x[M,512] @ W1.  BM=64, BN=256, BK=32.
// ---------------------------------------------------------------------------

#define G1_LDK 40

__global__ __launch_bounds__(256) void gemm1_mfma(const float* __restrict__ A,
                                                  const ushort* __restrict__ BT,
                                                  ushort* __restrict__ C, int M) {
    __shared__ ushort As[64 * G1_LDK];
    __shared__ ushort Bs[256 * G1_LDK];
    const int tid  = threadIdx.x;
    const int bm   = blockIdx.x * 64;
    const int wave = tid >> 6;
    const int lane = tid & 63;
    const int quad = lane >> 4;
    const int l16  = lane & 15;

    f32x4 acc[4][4] = {};

    const int ar = tid >> 2;
    const int ac = (tid & 3) * 8;

    for (int k0 = 0; k0 < F_IN; k0 += 32) {
        {
            int gr = bm + ar;
            float4 v0 = make_float4(0.f, 0.f, 0.f, 0.f), v1 = v0;
            if (gr < M) {
                const float* ap = A + (size_t)gr * F_IN + k0 + ac;
                v0 = *(const float4*)(ap);
                v1 = *(const float4*)(ap + 4);
            }
            uint4 w;
            w.x = pack2(v0.x, v0.y);
            w.y = pack2(v0.z, v0.w);
            w.z = pack2(v1.x, v1.y);
            w.w = pack2(v1.z, v1.w);
            *(uint4*)&As[ar * G1_LDK + ac] = w;
        }
#pragma unroll
        for (int p = 0; p < 4; ++p) {
            int idx = tid + p * 256;
            int r = idx >> 2;
            int c = (idx & 3) * 8;
            uint4 v = *(const uint4*)(BT + (size_t)r * F_IN + k0 + c);
            *(uint4*)&Bs[r * G1_LDK + c] = v;
        }
        __syncthreads();

        bf16x8 af[4], bfr[4];
#pragma unroll
        for (int mt = 0; mt < 4; ++mt)
            af[mt] = *(bf16x8*)&As[(mt * 16 + l16) * G1_LDK + quad * 8];
#pragma unroll
        for (int nt = 0; nt < 4; ++nt)
            bfr[nt] = *(bf16x8*)&Bs[(wave * 64 + nt * 16 + l16) * G1_LDK + quad * 8];
#pragma unroll
        for (int mt = 0; mt < 4; ++mt)
#pragma unroll
            for (int nt = 0; nt < 4; ++nt)
                acc[mt][nt] = __builtin_amdgcn_mfma_f32_16x16x32_bf16(af[mt], bfr[nt],
                                                                     acc[mt][nt], 0, 0, 0);
        __syncthreads();
    }

#pragma unroll
    for (int mt = 0; mt < 4; ++mt) {
#pragma unroll
        for (int i = 0; i < 4; ++i) {
            int row = bm + mt * 16 + quad * 4 + i;
            if (row < M) {
#pragma unroll
                for (int nt = 0; nt < 4; ++nt) {
                    int col = wave * 64 + nt * 16 + l16;
                    C[(size_t)row * F_HID + col] = f2b(acc[mt][nt][i]);
                }
            }
        }
    }
}

// ---------------------------------------------------------------------------
// Propagate layer 1 (F=256, bf16) + bias + ReLU. One wave per row; masked
// chunks of 8 keep 8 gathers in flight with no serially-dependent remainder.
// ---------------------------------------------------------------------------

#define P1U 8

__global__ __launch_bounds__(256) void prop1_kernel(const ushort* __restrict__ h,
                                                    const float* __restrict__ b1,
                                                    const float* __restrict__ dinv,
                                                    const int* __restrict__ rowptr,
                                                    const uint2* __restrict__ edge_s,
                                                    ushort* __restrict__ g, int N) {
    int wid  = (blockIdx.x * blockDim.x + threadIdx.x) >> 6;
    int lane = threadIdx.x & 63;
    if (wid >= N) return;
    float di = dinv[wid];
    float sn = di * di;
    ushort4 sv = ((const ushort4*)(h + (size_t)wid * F_HID))[lane];
    float ax = sn * b2f(sv.x), ay = sn * b2f(sv.y), az = sn * b2f(sv.z), aw = sn * b2f(sv.w);
    int e0 = rowptr[wid], e1 = rowptr[wid + 1];
    for (int e = e0; e < e1; e += P1U) {
        ushort4 v[P1U];
        float   w[P1U];
#pragma unroll
        for (int u = 0; u < P1U; ++u) {
            int idx = e + u;
            uint2 ev = edge_s[min(idx, e1 - 1)];
            w[u] = (idx < e1) ? __uint_as_float(ev.y) : 0.f;
            v[u] = ((const ushort4*)(h + (size_t)ev.x * F_HID))[lane];
        }
#pragma unroll
        for (int u = 0; u < P1U; ++u) {
            ax = fmaf(w[u], b2f(v[u].x), ax);
            ay = fmaf(w[u], b2f(v[u].y), ay);
            az = fmaf(w[u], b2f(v[u].z), az);
            aw = fmaf(w[u], b2f(v[u].w), aw);
        }
    }
    float4 bv = ((const float4*)b1)[lane];
    ax = fmaxf(ax + bv.x, 0.f);
    ay = fmaxf(ay + bv.y, 0.f);
    az = fmaxf(az + bv.z, 0.f);
    aw = fmaxf(aw + bv.w, 0.f);
    ushort4 o;
    o.x = f2b(ax); o.y = f2b(ay); o.z = f2b(az); o.w = f2b(aw);
    ((ushort4*)(g + (size_t)wid * F_HID))[lane] = o;
}

// ---------------------------------------------------------------------------
// GEMM2 (MFMA bf16): h2[M,40] = g[M,256] @ W2, K fully LDS-staged.
// ---------------------------------------------------------------------------

#define G2_LDK 264

__global__ __launch_bounds__(256) void gemm2_mfma(const ushort* __restrict__ G,
                                                  const ushort* __restrict__ BT,
                                                  ushort* __restrict__ H2, int M) {
    __shared__ ushort As[64 * G2_LDK];
    __shared__ ushort Bs[F_OUTP * G2_LDK];
    const int tid  = threadIdx.x;
    const int bm   = blockIdx.x * 64;
    const int wave = tid >> 6;
    const int lane = tid & 63;
    const int quad = lane >> 4;
    const int l16  = lane & 15;

#pragma unroll
    for (int p = 0; p < 8; ++p) {
        int idx = tid + p * 256;
        int r = idx >> 5;
        int c = (idx & 31) * 8;
        uint4 v = make_uint4(0, 0, 0, 0);
        int gr = bm + r;
        if (gr < M) v = *(const uint4*)(G + (size_t)gr * F_HID + c);
        *(uint4*)&As[r * G2_LDK + c] = v;
    }
#pragma unroll
    for (int p = 0; p < 6; ++p) {
        int idx = tid + p * 256;
        int r = idx >> 5;
        int c = (idx & 31) * 8;
        uint4 v = *(const uint4*)(BT + (size_t)r * F_HID + c);
        *(uint4*)&Bs[r * G2_LDK + c] = v;
    }
    __syncthreads();

    f32x4 acc[3] = {};
#pragma unroll
    for (int ks = 0; ks < F_HID / 32; ++ks) {
        bf16x8 a = *(bf16x8*)&As[(wave * 16 + l16) * G2_LDK + ks * 32 + quad * 8];
#pragma unroll
        for (int nt = 0; nt < 3; ++nt) {
            bf16x8 b = *(bf16x8*)&Bs[(nt * 16 + l16) * G2_LDK + ks * 32 + quad * 8];
            acc[nt] = __builtin_amdgcn_mfma_f32_16x16x32_bf16(a, b, acc[nt], 0, 0, 0);
        }
    }

#pragma unroll
    for (int i = 0; i < 4; ++i) {
        int row = bm + wave * 16 + quad * 4 + i;
        if (row < M) {
#pragma unroll
            for (int nt = 0; nt < 3; ++nt) {
                int col = nt * 16 + l16;
                if (col < F_OUT)
                    H2[(size_t)row * F_OUT + col] = f2b(acc[nt][i]);
            }
        }
    }
}

// ---------------------------------------------------------------------------
// Propagate layer 2 (F=40, bf16 in) + bias + fused log_softmax.
// ---------------------------------------------------------------------------

#define P2U 8

__global__ __launch_bounds__(256) void prop2_kernel(const ushort* __restrict__ h2,
                                                    const float* __restrict__ b2,
                                                    const float* __restrict__ dinv,
                                                    const int* __restrict__ rowptr,
                                                    const uint2* __restrict__ edge_s,
                                                    float* __restrict__ out, int N) {
    int wid  = (blockIdx.x * blockDim.x + threadIdx.x) >> 6;
    int lane = threadIdx.x & 63;
    if (wid >= N) return;
    int li = (lane < F_OUT) ? lane : 0;
    float di = dinv[wid];
    float sn = di * di;
    float acc = sn * b2f(h2[(size_t)wid * F_OUT + li]);
    int e0 = rowptr[wid], e1 = rowptr[wid + 1];
    for (int e = e0; e < e1; e += P2U) {
        ushort v[P2U];
        float  w[P2U];
#pragma unroll
        for (int u = 0; u < P2U; ++u) {
            int idx = e + u;
            uint2 ev = edge_s[min(idx, e1 - 1)];
            w[u] = (idx < e1) ? __uint_as_float(ev.y) : 0.f;
            v[u] = h2[(size_t)ev.x * F_OUT + li];
        }
#pragma unroll
        for (int u = 0; u < P2U; ++u) acc = fmaf(w[u], b2f(v[u]), acc);
    }
    acc += b2[li];

    float a = (lane < F_OUT) ? acc : -INFINITY;
    float m = a;
#pragma unroll
    for (int o = 32; o; o >>= 1) m = fmaxf(m, __shfl_xor(m, o, 64));
    float ex = (lane < F_OUT) ? expf(acc - m) : 0.f;
    float s = ex;
#pragma unroll
    for (int o = 32; o; o >>= 1) s += __shfl_xor(s, o, 64);
    if (lane < F_OUT) {
        size_t base = (size_t)wid * F_OUT + lane;
        out[base] = acc;
        out[(size_t)N * F_OUT + base] = acc - m - logf(s);
    }
}

// ---------------------------------------------------------------------------
// Launch
// ---------------------------------------------------------------------------

extern "C" void kernel_launch(void* const* d_in, const int* in_sizes, int n_in,
                              void* d_out, int out_size, void* d_ws, size_t ws_size,
                              hipStream_t stream) {
    const float* x  = (const float*)d_in[0];
    const int*   ei = (const int*)d_in[1];
    const float* W1 = (const float*)d_in[2];
    const float* b1 = (const float*)d_in[3];
    const float* W2 = (const float*)d_in[4];
    const float* b2 = (const float*)d_in[5];
    float* out = (float*)d_out;

    const int N = in_sizes[0] / F_IN;
    const int E = in_sizes[1] / 2;
    const int* row = ei;
    const int* col = ei + E;
    const int NR = (N + HBINS - 1) / HBINS;

    char* p = (char*)d_ws;
    auto alloc = [&](size_t bytes) -> char* {
        char* q = p;
        p += (bytes + 255) & ~(size_t)255;
        return q;
    };
    int*    cnt_row = (int*)alloc((size_t)N * 4);
    int*    rowptr  = (int*)alloc((size_t)(N + 1) * 4);
    int*    cursor  = (int*)alloc((size_t)N * 4);
    float*  dinv    = (float*)alloc((size_t)N * 4);
    uint2*  edge_s  = (uint2*)alloc((size_t)E * 8);
    int*    part    = (int*)alloc((size_t)2 * NR * HSLICES * HBINS * 4);
    ushort* W1T     = (ushort*)alloc((size_t)F_HID * F_IN * 2);
    ushort* W2T     = (ushort*)alloc((size_t)F_OUTP * F_HID * 2);
    ushort* h       = (ushort*)alloc((size_t)N * F_HID * 2);
    ushort* g       = (ushort*)alloc((size_t)N * F_HID * 2);
    ushort* h2      = (ushort*)alloc((size_t)N * F_OUT * 2);

    dim3 hgrid(HSLICES, NR, 2);
    hist_kernel<<<hgrid, 1024, 0, stream>>>(ei, part, E, NR);
    hist_reduce<<<(2 * N + 255) / 256, 256, 0, stream>>>(part, cnt_row, dinv, N, NR);
    scan_kernel<<<1, 1024, 0, stream>>>(cnt_row, rowptr, cursor, N);
    scatter_kernel<<<(E + 255) / 256, 256, 0, stream>>>(row, col, dinv, cursor, edge_s, E);

    int prep_total = F_HID * F_IN + F_OUTP * F_HID;
    prep_weights<<<(prep_total + 255) / 256, 256, 0, stream>>>(W1, W2, W1T, W2T);

    gemm1_mfma<<<(N + 63) / 64, 256, 0, stream>>>(x, W1T, h, N);
    prop1_kernel<<<(N + 3) / 4, 256, 0, stream>>>(h, b1, dinv, rowptr, edge_s, g, N);
    gemm2_mfma<<<(N + 63) / 64, 256, 0, stream>>>(g, W2T, h2, N);
    prop2_kernel<<<(N + 3) / 4, 256, 0, stream>>>(h2, b2, dinv, rowptr, edge_s, out, N);
}

// Round 5
// 1098.560 us; speedup vs baseline: 1.9875x; 1.1026x over previous
//
#include <hip/hip_runtime.h>
#include <cstdint>
#include <cstddef>

#define F_IN  512
#define F_HID 256
#define F_OUT 40
#define F_OUTP 48   // padded to 3x16 MFMA tiles

#define HBINS 16384        // 64 KB LDS histogram bins
#define HSLICES 36         // edge slices for hist/place passes

typedef short  bf16x8 __attribute__((ext_vector_type(8)));
typedef float  f32x4  __attribute__((ext_vector_type(4)));

__device__ __forceinline__ ushort f2b(float f) {   // fp32 -> bf16 RNE
    uint u = __float_as_uint(f);
    return (ushort)((u + 0x7FFFu + ((u >> 16) & 1u)) >> 16);
}
__device__ __forceinline__ uint pack2(float a, float b) {
    return (uint)f2b(a) | ((uint)f2b(b) << 16);
}
__device__ __forceinline__ float b2f(ushort u) {
    return __uint_as_float(((uint)u) << 16);
}

// ---------------------------------------------------------------------------
// Degree histogram WITHOUT global atomics: block (slice s, range r, array a)
// scans its edge slice, counts indices in [r*HBINS, r*HBINS+HBINS) into an LDS
// histogram, writes the 64 KB partial to scratch non-atomically.
// ---------------------------------------------------------------------------

__global__ __launch_bounds__(1024) void hist_kernel(const int* __restrict__ ei,
                                                    int* __restrict__ part,
                                                    int E, int NR) {
    __shared__ int hist[HBINS];
    const int tid = threadIdx.x;
    const int s = blockIdx.x;
    const int r = blockIdx.y;
    const int a = blockIdx.z;
    const int* src = ei + (size_t)a * E;   // a=0: row, a=1: col
    const uint base = (uint)r * HBINS;

    for (int i = tid; i < HBINS; i += 1024) hist[i] = 0;
    __syncthreads();

    int elen  = (E + HSLICES - 1) / HSLICES;
    int start = s * elen;
    int end   = min(start + elen, E);
    for (int i = start + tid; i < end; i += 1024) {
        uint b = (uint)src[i] - base;
        if (b < HBINS) atomicAdd(&hist[b], 1);
    }
    __syncthreads();

    int* dst = part + ((size_t)(a * NR + r) * HSLICES + s) * HBINS;
    for (int i = tid; i < HBINS; i += 1024) dst[i] = hist[i];
}

// Sum the HSLICES partials per (array, node). a=0 -> cnt_row; a=1 -> dinv.
__global__ void hist_reduce(const int* __restrict__ part,
                            int* __restrict__ cnt_row,
                            float* __restrict__ dinv, int N, int NR) {
    int t = blockIdx.x * blockDim.x + threadIdx.x;
    if (t >= 2 * N) return;
    int a = (t >= N) ? 1 : 0;
    int i = t - a * N;
    int r = i >> 14;             // / HBINS
    int bin = i & (HBINS - 1);
    const int* p = part + ((size_t)(a * NR + r) * HSLICES) * HBINS + bin;
    int sum = 0;
#pragma unroll 4
    for (int s = 0; s < HSLICES; ++s) sum += p[(size_t)s * HBINS];
    if (a == 0) cnt_row[i] = sum;
    else        dinv[i] = rsqrtf((float)(sum + 1));
}

// ---------------------------------------------------------------------------
// Single-block exclusive scan of cnt_row -> rowptr[N+1].
// ---------------------------------------------------------------------------

__global__ __launch_bounds__(1024) void scan_kernel(const int* __restrict__ cnt,
                                                    int* __restrict__ rowptr, int N) {
    __shared__ int sums[1024];
    int tid = threadIdx.x;
    int chunk = (N + 1023) >> 10;
    int s0 = tid * chunk;
    int s1 = s0 + chunk;
    if (s0 > N) s0 = N;
    if (s1 > N) s1 = N;
    int sum = 0;
    for (int i = s0; i < s1; ++i) sum += cnt[i];
    sums[tid] = sum;
    __syncthreads();
    for (int off = 1; off < 1024; off <<= 1) {
        int v = (tid >= off) ? sums[tid - off] : 0;
        __syncthreads();
        sums[tid] += v;
        __syncthreads();
    }
    int base = (tid > 0) ? sums[tid - 1] : 0;
    for (int i = s0; i < s1; ++i) {
        rowptr[i] = base;
        base += cnt[i];
    }
    if (tid == 0) rowptr[N] = sums[1023];
}

// ---------------------------------------------------------------------------
// offs[r][s][bin] = rowptr[node] + sum_{s'<s} part[a=0][r][s'][bin].
// One thread per node; per-s writes are lane-consecutive -> coalesced.
// ---------------------------------------------------------------------------

__global__ void slice_scan(const int* __restrict__ part,
                           const int* __restrict__ rowptr,
                           int* __restrict__ offs, int N, int NR) {
    int i = blockIdx.x * blockDim.x + threadIdx.x;
    if (i >= NR * HBINS) return;
    int r = i >> 14;
    int bin = i & (HBINS - 1);
    int acc = (i < N) ? rowptr[i] : 0;
    const int* p = part + ((size_t)r * HSLICES) * HBINS + bin;   // a=0 block
    int* o = offs + ((size_t)r * HSLICES) * HBINS + bin;
    for (int s = 0; s < HSLICES; ++s) {
        o[(size_t)s * HBINS] = acc;
        acc += p[(size_t)s * HBINS];
    }
}

// ---------------------------------------------------------------------------
// CSR placement with LDS cursors only (no global atomics). Block (s, r) loads
// its offset slab into LDS, re-scans its edge slice, places in-range edges.
// ---------------------------------------------------------------------------

__global__ __launch_bounds__(1024) void place_kernel(const int* __restrict__ ei,
                                                     const float* __restrict__ dinv,
                                                     const int* __restrict__ offs,
                                                     uint2* __restrict__ edge_s,
                                                     int E, int NR) {
    __shared__ int cur[HBINS];
    const int tid = threadIdx.x;
    const int s = blockIdx.x;
    const int r = blockIdx.y;
    const int* row = ei;
    const int* col = ei + E;
    const uint base = (uint)r * HBINS;
    const int* oslab = offs + ((size_t)r * HSLICES + s) * HBINS;

    for (int i = tid; i < HBINS; i += 1024) cur[i] = oslab[i];
    __syncthreads();

    int elen  = (E + HSLICES - 1) / HSLICES;
    int start = s * elen;
    int end   = min(start + elen, E);
    for (int i = start + tid; i < end; i += 1024) {
        uint b = (uint)row[i] - base;
        if (b < HBINS) {
            int pos = atomicAdd(&cur[b], 1);
            int c = col[i];
            uint2 v;
            v.x = (uint)c;
            v.y = __float_as_uint(dinv[base + b] * dinv[c]);
            edge_s[pos] = v;
        }
    }
}

// ---------------------------------------------------------------------------
// Weight prep: W1T [256][512] bf16 (= W1^T), W2T [48][256] bf16 (rows 40..47=0).
// ---------------------------------------------------------------------------

__global__ void prep_weights(const float* __restrict__ W1, const float* __restrict__ W2,
                             ushort* __restrict__ W1T, ushort* __restrict__ W2T) {
    int t = blockIdx.x * blockDim.x + threadIdx.x;
    if (t < F_HID * F_IN) {
        int n = t >> 9, k = t & 511;
        W1T[t] = f2b(W1[(size_t)k * F_HID + n]);
        return;
    }
    int u = t - F_HID * F_IN;
    if (u < F_OUTP * F_HID) {
        int n = u >> 8, k = u & 255;
        W2T[u] = f2b((n < F_OUT) ? W2[(size_t)k * F_OUT + n] : 0.f);
    }
}

// ---------------------------------------------------------------------------
// GEMM1 (MFMA bf16): h[M,256] = x[M,512] @ W1.  BM=64, BN=256, BK=32.
// ---------------------------------------------------------------------------

#define G1_LDK 40

__global__ __launch_bounds__(256) void gemm1_mfma(const float* __restrict__ A,
                                                  const ushort* __restrict__ BT,
                                                  ushort* __restrict__ C, int M) {
    __shared__ ushort As[64 * G1_LDK];
    __shared__ ushort Bs[256 * G1_LDK];
    const int tid  = threadIdx.x;
    const int bm   = blockIdx.x * 64;
    const int wave = tid >> 6;
    const int lane = tid & 63;
    const int quad = lane >> 4;
    const int l16  = lane & 15;

    f32x4 acc[4][4] = {};

    const int ar = tid >> 2;
    const int ac = (tid & 3) * 8;

    for (int k0 = 0; k0 < F_IN; k0 += 32) {
        {
            int gr = bm + ar;
            float4 v0 = make_float4(0.f, 0.f, 0.f, 0.f), v1 = v0;
            if (gr < M) {
                const float* ap = A + (size_t)gr * F_IN + k0 + ac;
                v0 = *(const float4*)(ap);
                v1 = *(const float4*)(ap + 4);
            }
            uint4 w;
            w.x = pack2(v0.x, v0.y);
            w.y = pack2(v0.z, v0.w);
            w.z = pack2(v1.x, v1.y);
            w.w = pack2(v1.z, v1.w);
            *(uint4*)&As[ar * G1_LDK + ac] = w;
        }
#pragma unroll
        for (int p = 0; p < 4; ++p) {
            int idx = tid + p * 256;
            int r = idx >> 2;
            int c = (idx & 3) * 8;
            uint4 v = *(const uint4*)(BT + (size_t)r * F_IN + k0 + c);
            *(uint4*)&Bs[r * G1_LDK + c] = v;
        }
        __syncthreads();

        bf16x8 af[4], bfr[4];
#pragma unroll
        for (int mt = 0; mt < 4; ++mt)
            af[mt] = *(bf16x8*)&As[(mt * 16 + l16) * G1_LDK + quad * 8];
#pragma unroll
        for (int nt = 0; nt < 4; ++nt)
            bfr[nt] = *(bf16x8*)&Bs[(wave * 64 + nt * 16 + l16) * G1_LDK + quad * 8];
#pragma unroll
        for (int mt = 0; mt < 4; ++mt)
#pragma unroll
            for (int nt = 0; nt < 4; ++nt)
                acc[mt][nt] = __builtin_amdgcn_mfma_f32_16x16x32_bf16(af[mt], bfr[nt],
                                                                     acc[mt][nt], 0, 0, 0);
        __syncthreads();
    }

#pragma unroll
    for (int mt = 0; mt < 4; ++mt) {
#pragma unroll
        for (int i = 0; i < 4; ++i) {
            int row = bm + mt * 16 + quad * 4 + i;
            if (row < M) {
#pragma unroll
                for (int nt = 0; nt < 4; ++nt) {
                    int col = wave * 64 + nt * 16 + l16;
                    C[(size_t)row * F_HID + col] = f2b(acc[mt][nt][i]);
                }
            }
        }
    }
}

// ---------------------------------------------------------------------------
// Propagate layer 1 (F=256, bf16) + bias + ReLU. One wave per row; masked
// chunks of 8 keep 8 gathers in flight with no serially-dependent remainder.
// At the measured ~6.6 TB/s effective gather ceiling.
// ---------------------------------------------------------------------------

#define P1U 8

__global__ __launch_bounds__(256) void prop1_kernel(const ushort* __restrict__ h,
                                                    const float* __restrict__ b1,
                                                    const float* __restrict__ dinv,
                                                    const int* __restrict__ rowptr,
                                                    const uint2* __restrict__ edge_s,
                                                    ushort* __restrict__ g, int N) {
    int wid  = (blockIdx.x * blockDim.x + threadIdx.x) >> 6;
    int lane = threadIdx.x & 63;
    if (wid >= N) return;
    float di = dinv[wid];
    float sn = di * di;
    ushort4 sv = ((const ushort4*)(h + (size_t)wid * F_HID))[lane];
    float ax = sn * b2f(sv.x), ay = sn * b2f(sv.y), az = sn * b2f(sv.z), aw = sn * b2f(sv.w);
    int e0 = rowptr[wid], e1 = rowptr[wid + 1];
    for (int e = e0; e < e1; e += P1U) {
        ushort4 v[P1U];
        float   w[P1U];
#pragma unroll
        for (int u = 0; u < P1U; ++u) {
            int idx = e + u;
            uint2 ev = edge_s[min(idx, e1 - 1)];
            w[u] = (idx < e1) ? __uint_as_float(ev.y) : 0.f;
            v[u] = ((const ushort4*)(h + (size_t)ev.x * F_HID))[lane];
        }
#pragma unroll
        for (int u = 0; u < P1U; ++u) {
            ax = fmaf(w[u], b2f(v[u].x), ax);
            ay = fmaf(w[u], b2f(v[u].y), ay);
            az = fmaf(w[u], b2f(v[u].z), az);
            aw = fmaf(w[u], b2f(v[u].w), aw);
        }
    }
    float4 bv = ((const float4*)b1)[lane];
    ax = fmaxf(ax + bv.x, 0.f);
    ay = fmaxf(ay + bv.y, 0.f);
    az = fmaxf(az + bv.z, 0.f);
    aw = fmaxf(aw + bv.w, 0.f);
    ushort4 o;
    o.x = f2b(ax); o.y = f2b(ay); o.z = f2b(az); o.w = f2b(aw);
    ((ushort4*)(g + (size_t)wid * F_HID))[lane] = o;
}

// ---------------------------------------------------------------------------
// GEMM2 (MFMA bf16): h2[M,40] = g[M,256] @ W2, K fully LDS-staged.
// ---------------------------------------------------------------------------

#define G2_LDK 264

__global__ __launch_bounds__(256) void gemm2_mfma(const ushort* __restrict__ G,
                                                  const ushort* __restrict__ BT,
                                                  ushort* __restrict__ H2, int M) {
    __shared__ ushort As[64 * G2_LDK];
    __shared__ ushort Bs[F_OUTP * G2_LDK];
    const int tid  = threadIdx.x;
    const int bm   = blockIdx.x * 64;
    const int wave = tid >> 6;
    const int lane = tid & 63;
    const int quad = lane >> 4;
    const int l16  = lane & 15;

#pragma unroll
    for (int p = 0; p < 8; ++p) {
        int idx = tid + p * 256;
        int r = idx >> 5;
        int c = (idx & 31) * 8;
        uint4 v = make_uint4(0, 0, 0, 0);
        int gr = bm + r;
        if (gr < M) v = *(const uint4*)(G + (size_t)gr * F_HID + c);
        *(uint4*)&As[r * G2_LDK + c] = v;
    }
#pragma unroll
    for (int p = 0; p < 6; ++p) {
        int idx = tid + p * 256;
        int r = idx >> 5;
        int c = (idx & 31) * 8;
        uint4 v = *(const uint4*)(BT + (size_t)r * F_HID + c);
        *(uint4*)&Bs[r * G2_LDK + c] = v;
    }
    __syncthreads();

    f32x4 acc[3] = {};
#pragma unroll
    for (int ks = 0; ks < F_HID / 32; ++ks) {
        bf16x8 a = *(bf16x8*)&As[(wave * 16 + l16) * G2_LDK + ks * 32 + quad * 8];
#pragma unroll
        for (int nt = 0; nt < 3; ++nt) {
            bf16x8 b = *(bf16x8*)&Bs[(nt * 16 + l16) * G2_LDK + ks * 32 + quad * 8];
            acc[nt] = __builtin_amdgcn_mfma_f32_16x16x32_bf16(a, b, acc[nt], 0, 0, 0);
        }
    }

#pragma unroll
    for (int i = 0; i < 4; ++i) {
        int row = bm + wave * 16 + quad * 4 + i;
        if (row < M) {
#pragma unroll
            for (int nt = 0; nt < 3; ++nt) {
                int col = nt * 16 + l16;
                if (col < F_OUT)
                    H2[(size_t)row * F_OUT + col] = f2b(acc[nt][i]);
            }
        }
    }
}

// ---------------------------------------------------------------------------
// Propagate layer 2 (F=40, bf16 in) + bias + fused log_softmax.
// ---------------------------------------------------------------------------

#define P2U 8

__global__ __launch_bounds__(256) void prop2_kernel(const ushort* __restrict__ h2,
                                                    const float* __restrict__ b2,
                                                    const float* __restrict__ dinv,
                                                    const int* __restrict__ rowptr,
                                                    const uint2* __restrict__ edge_s,
                                                    float* __restrict__ out, int N) {
    int wid  = (blockIdx.x * blockDim.x + threadIdx.x) >> 6;
    int lane = threadIdx.x & 63;
    if (wid >= N) return;
    int li = (lane < F_OUT) ? lane : 0;
    float di = dinv[wid];
    float sn = di * di;
    float acc = sn * b2f(h2[(size_t)wid * F_OUT + li]);
    int e0 = rowptr[wid], e1 = rowptr[wid + 1];
    for (int e = e0; e < e1; e += P2U) {
        ushort v[P2U];
        float  w[P2U];
#pragma unroll
        for (int u = 0; u < P2U; ++u) {
            int idx = e + u;
            uint2 ev = edge_s[min(idx, e1 - 1)];
            w[u] = (idx < e1) ? __uint_as_float(ev.y) : 0.f;
            v[u] = h2[(size_t)ev.x * F_OUT + li];
        }
#pragma unroll
        for (int u = 0; u < P2U; ++u) acc = fmaf(w[u], b2f(v[u]), acc);
    }
    acc += b2[li];

    float a = (lane < F_OUT) ? acc : -INFINITY;
    float m = a;
#pragma unroll
    for (int o = 32; o; o >>= 1) m = fmaxf(m, __shfl_xor(m, o, 64));
    float ex = (lane < F_OUT) ? expf(acc - m) : 0.f;
    float s = ex;
#pragma unroll
    for (int o = 32; o; o >>= 1) s += __shfl_xor(s, o, 64);
    if (lane < F_OUT) {
        size_t base = (size_t)wid * F_OUT + lane;
        out[base] = acc;
        out[(size_t)N * F_OUT + base] = acc - m - logf(s);
    }
}

// ---------------------------------------------------------------------------
// Launch
// ---------------------------------------------------------------------------

extern "C" void kernel_launch(void* const* d_in, const int* in_sizes, int n_in,
                              void* d_out, int out_size, void* d_ws, size_t ws_size,
                              hipStream_t stream) {
    const float* x  = (const float*)d_in[0];
    const int*   ei = (const int*)d_in[1];
    const float* W1 = (const float*)d_in[2];
    const float* b1 = (const float*)d_in[3];
    const float* W2 = (const float*)d_in[4];
    const float* b2 = (const float*)d_in[5];
    float* out = (float*)d_out;

    const int N = in_sizes[0] / F_IN;
    const int E = in_sizes[1] / 2;
    const int NR = (N + HBINS - 1) / HBINS;

    char* p = (char*)d_ws;
    auto alloc = [&](size_t bytes) -> char* {
        char* q = p;
        p += (bytes + 255) & ~(size_t)255;
        return q;
    };
    int*    cnt_row = (int*)alloc((size_t)N * 4);
    int*    rowptr  = (int*)alloc((size_t)(N + 1) * 4);
    float*  dinv    = (float*)alloc((size_t)N * 4);
    uint2*  edge_s  = (uint2*)alloc((size_t)E * 8);
    int*    part    = (int*)alloc((size_t)2 * NR * HSLICES * HBINS * 4);
    int*    offs    = (int*)alloc((size_t)NR * HSLICES * HBINS * 4);
    ushort* W1T     = (ushort*)alloc((size_t)F_HID * F_IN * 2);
    ushort* W2T     = (ushort*)alloc((size_t)F_OUTP * F_HID * 2);
    ushort* h       = (ushort*)alloc((size_t)N * F_HID * 2);
    ushort* g       = (ushort*)alloc((size_t)N * F_HID * 2);
    ushort* h2      = (ushort*)alloc((size_t)N * F_OUT * 2);

    dim3 hgrid(HSLICES, NR, 2);
    hist_kernel<<<hgrid, 1024, 0, stream>>>(ei, part, E, NR);
    hist_reduce<<<(2 * N + 255) / 256, 256, 0, stream>>>(part, cnt_row, dinv, N, NR);
    scan_kernel<<<1, 1024, 0, stream>>>(cnt_row, rowptr, N);
    slice_scan<<<(NR * HBINS + 255) / 256, 256, 0, stream>>>(part, rowptr, offs, N, NR);

    dim3 pgrid(HSLICES, NR);
    place_kernel<<<pgrid, 1024, 0, stream>>>(ei, dinv, offs, edge_s, E, NR);

    int prep_total = F_HID * F_IN + F_OUTP * F_HID;
    prep_weights<<<(prep_total + 255) / 256, 256, 0, stream>>>(W1, W2, W1T, W2T);

    gemm1_mfma<<<(N + 63) / 64, 256, 0, stream>>>(x, W1T, h, N);
    prop1_kernel<<<(N + 3) / 4, 256, 0, stream>>>(h, b1, dinv, rowptr, edge_s, g, N);
    gemm2_mfma<<<(N + 63) / 64, 256, 0, stream>>>(g, W2T, h2, N);
    prop2_kernel<<<(N + 3) / 4, 256, 0, stream>>>(h2, b2, dinv, rowptr, edge_s, out, N);
}